// Round 9
// baseline (663.633 us; speedup 1.0000x reference)
//
#include <hip/hip_runtime.h>
#include <math.h>

#define N_NODES 100000
#define N_EDGES 3200000
#define IN_F 256
#define OUT_F 64
#define LRELU_ALPHA 0.2f
#define NBKT 782    // src buckets: 128 nodes each
#define CAP 4480    // src bucket capacity: mean 4096 + 6 sigma
#define NBKTD 98    // dst coarse buckets: 1024 nodes each
#define CAPD 34304  // dst bucket capacity: mean 32653 + ~9 sigma

typedef unsigned short u16;
typedef __attribute__((ext_vector_type(8))) short short8;
typedef __attribute__((ext_vector_type(4))) float floatx4;

__device__ inline u16 f2bf(float f) {  // RNE fp32 -> bf16
  unsigned u = __float_as_uint(f);
  u += 0x7FFFu + ((u >> 16) & 1u);
  return (u16)(u >> 16);
}
__device__ inline float bf2f(u16 h) {
  return __uint_as_float(((unsigned)h) << 16);
}

// ---------------------------------------------------------------------------
// prep: blocks 0..63 convert W to bf16; block 64 zeros fill ctrs (PADDED:
// one counter per 64B line, stride 16 ints); blocks 65..164 zero denom.
// ---------------------------------------------------------------------------
__global__ __launch_bounds__(256) void k_prep(const float* __restrict__ W,
                                              u16* __restrict__ Wbf,
                                              int* __restrict__ sfill,
                                              int* __restrict__ dfill,
                                              float* __restrict__ denom) {
  if (blockIdx.x < 64) {
    int i = blockIdx.x * 256 + threadIdx.x;
    Wbf[i] = f2bf(W[i]);
  } else if (blockIdx.x == 64) {
    for (int i = threadIdx.x; i < NBKT * 16; i += 256) sfill[i] = 0;
    for (int i = threadIdx.x; i < NBKTD * 16; i += 256) dfill[i] = 0;
  } else {
    int i4 = (blockIdx.x - 65) * 256 + threadIdx.x;
    if (i4 < 25000) {
      ((float4*)denom)[i4] = make_float4(0.f, 0.f, 0.f, 0.f);
    }
  }
}

// ---------------------------------------------------------------------------
// linear via bf16 MFMA: h = x@W^T + b (stored bf16); s1 = h.a1; s2 = h.a2
// ---------------------------------------------------------------------------
__global__ __launch_bounds__(256) void k_linear(
    const float* __restrict__ x, const u16* __restrict__ Wbf,
    const float* __restrict__ b, const float* __restrict__ a,
    u16* __restrict__ hbf, float* __restrict__ s1, float* __restrict__ s2) {
  __shared__ u16 Wlds[64 * 264];

  const int t = threadIdx.x;
#pragma unroll
  for (int p = 0; p < 8; p++) {
    int c = p * 256 + t;
    int row = c >> 5;
    int kc = (c & 31) * 8;
    *(short8*)&Wlds[row * 264 + kc] = *(const short8*)&Wbf[row * 256 + kc];
  }
  __syncthreads();

  const int w = t >> 6;
  const int lane = t & 63;
  const int col = lane & 15;
  const int q = lane >> 4;
  const int m0 = blockIdx.x * 64 + w * 16;

  floatx4 acc[4];
#pragma unroll
  for (int nt = 0; nt < 4; nt++) acc[nt] = (floatx4){0.f, 0.f, 0.f, 0.f};

  int mrow = m0 + col;
  if (mrow > N_NODES - 1) mrow = N_NODES - 1;
  const float* xrow = x + (size_t)mrow * IN_F + q * 8;

#pragma unroll
  for (int kk = 0; kk < 8; kk++) {
    float4 f0 = *(const float4*)(xrow + kk * 32);
    float4 f1 = *(const float4*)(xrow + kk * 32 + 4);
    short8 af;
    af[0] = (short)f2bf(f0.x);
    af[1] = (short)f2bf(f0.y);
    af[2] = (short)f2bf(f0.z);
    af[3] = (short)f2bf(f0.w);
    af[4] = (short)f2bf(f1.x);
    af[5] = (short)f2bf(f1.y);
    af[6] = (short)f2bf(f1.z);
    af[7] = (short)f2bf(f1.w);
#pragma unroll
    for (int nt = 0; nt < 4; nt++) {
      short8 bfr = *(const short8*)&Wlds[(nt * 16 + col) * 264 + kk * 32 + q * 8];
      acc[nt] = __builtin_amdgcn_mfma_f32_16x16x32_bf16(af, bfr, acc[nt], 0, 0, 0);
    }
  }

  float bv[4], a1v[4], a2v[4];
#pragma unroll
  for (int nt = 0; nt < 4; nt++) {
    bv[nt] = b[nt * 16 + col];
    a1v[nt] = a[nt * 16 + col];
    a2v[nt] = a[OUT_F + nt * 16 + col];
  }
#pragma unroll
  for (int r = 0; r < 4; r++) {
    int node = m0 + q * 4 + r;
    float p1 = 0.f, p2 = 0.f;
#pragma unroll
    for (int nt = 0; nt < 4; nt++) {
      float hv = acc[nt][r] + bv[nt];
      if (node < N_NODES) hbf[(size_t)node * OUT_F + nt * 16 + col] = f2bf(hv);
      p1 = fmaf(hv, a1v[nt], p1);
      p2 = fmaf(hv, a2v[nt], p2);
    }
#pragma unroll
    for (int s = 1; s < 16; s <<= 1) {
      p1 += __shfl_xor(p1, s, 16);
      p2 += __shfl_xor(p2, s, 16);
    }
    if (col == 0 && node < N_NODES) {
      s1[node] = p1;
      s2[node] = p2;
    }
  }
}

// ---------------------------------------------------------------------------
// place: ex = exp(leakyrelu(s1[src]+s2[dst])); write into PADDED buckets.
// R9: EPT_P=16 (8192 edges/block) with TWO-WINDOW staged flush. Histogram/
// reserve cover 8192 edges -> S flush runs average 10.5 entries (84B, ~1.25x
// line amp, was 5.2/1.56x at R7; R8's 2.6/4x proved run length dominates).
// Stage LDS stays 4096 entries: scatter entries with idx<4096 -> flush ->
// scatter idx>=4096 into the same window -> flush. (bk,rk) packed into one
// int to hold VGPRs at ~6 waves/SIMD.
// pairS = float2 (ex, d | (s&127)<<17)  src-bucketed (128-node)
// pairD = u32 (bf16(ex)<<16 | d&1023)   dst-bucketed (1024-node)
// ---------------------------------------------------------------------------
#define PBT 512
#define EPT_P 16
#define PEB (PBT * EPT_P)  // 8192 edges per block
#define WIN 4096           // stage window entries
__global__ __launch_bounds__(PBT, 6) void k_place(
    const int* __restrict__ src, const int* __restrict__ dst,
    const float* __restrict__ s1, const float* __restrict__ s2,
    int* __restrict__ sfill, int* __restrict__ dfill,
    float2* __restrict__ pairS, unsigned* __restrict__ pairD) {
  __shared__ int lc[NBKT];     // histogram (counts after pass 1)
  __shared__ int ofs[NBKT];    // block-local stage offset
  __shared__ int gbase[NBKT];  // (bkt*cap + fillbase - ofs)
  __shared__ int tot;          // block-local stage allocator
  __shared__ float2 stage[WIN];
  __shared__ u16 stageB[WIN];  // bucket id per stage entry

  const int t = threadIdx.x;
  const int side = blockIdx.y;  // 0 = S (src-bucket), 1 = D (dst-bucket)
  const int base = blockIdx.x * PEB + t;
  const int nb = side ? NBKTD : NBKT;

  for (int i = t; i < nb; i += PBT) lc[i] = 0;
  if (t == 0) tot = 0;
  __syncthreads();

  // ---- pass A: all adj loads in flight ----
  int sa[EPT_P], da[EPT_P];
#pragma unroll
  for (int j = 0; j < EPT_P; j++) {
    int e = base + j * PBT;
    int ec = e < N_EDGES ? e : N_EDGES - 1;
    sa[j] = src[ec];
    da[j] = dst[ec];
  }
  // ---- pass B: all s1/s2 gathers in flight ----
  float g1[EPT_P], g2[EPT_P];
#pragma unroll
  for (int j = 0; j < EPT_P; j++) {
    g1[j] = s1[sa[j]];
    g2[j] = s2[da[j]];
  }
  // ---- pass C: math + keys ----
  float ex[EPT_P];
  int key[EPT_P], bk[EPT_P];
#pragma unroll
  for (int j = 0; j < EPT_P; j++) {
    float v = g1[j] + g2[j];
    v = v > 0.f ? v : LRELU_ALPHA * v;
    ex[j] = __expf(v);
    if (side == 0) {
      key[j] = da[j] | ((sa[j] & 127) << 17);
      bk[j] = sa[j] >> 7;
    } else {
      key[j] = da[j] & 1023;
      bk[j] = da[j] >> 10;
    }
    if (base + j * PBT >= N_EDGES) bk[j] = -1;
  }
  // ---- pass D: count; pack (bk,rk) into pk = bk<<13 | rk ----
  int pk[EPT_P];
#pragma unroll
  for (int j = 0; j < EPT_P; j++) {
    pk[j] = (bk[j] >= 0) ? ((bk[j] << 13) | atomicAdd(&lc[bk[j]], 1)) : -1;
  }
  __syncthreads();

  // ---- reserve global + local ranges (padded counters: stride 16) ----
  int* fill = side ? dfill : sfill;
  const int capb = side ? CAPD : CAP;
  for (int i = t; i < nb; i += PBT) {
    int c = lc[i];
    if (c) {
      int o = atomicAdd(&tot, c);
      ofs[i] = o;
      gbase[i] = i * capb + atomicAdd(&fill[i << 4], c) - o;
    }
  }
  __syncthreads();
  const int nval = tot;  // # valid edges this block
  const int lim0 = nval < WIN ? nval : WIN;

  if (side == 0) {
    // ---- S window 0: scatter idx<WIN ----
#pragma unroll
    for (int j = 0; j < EPT_P; j++) {
      if (pk[j] >= 0) {
        int bkt = pk[j] >> 13;
        int idx = ofs[bkt] + (pk[j] & 8191);
        if (idx < WIN) {
          stage[idx] = make_float2(ex[j], __int_as_float(key[j]));
          stageB[idx] = (u16)bkt;
        }
      }
    }
    __syncthreads();
    for (int i = t; i < lim0; i += PBT) {
      pairS[gbase[stageB[i]] + i] = stage[i];
    }
    __syncthreads();
    // ---- S window 1: scatter idx>=WIN ----
#pragma unroll
    for (int j = 0; j < EPT_P; j++) {
      if (pk[j] >= 0) {
        int bkt = pk[j] >> 13;
        int idx = ofs[bkt] + (pk[j] & 8191);
        if (idx >= WIN) {
          stage[idx - WIN] = make_float2(ex[j], __int_as_float(key[j]));
          stageB[idx - WIN] = (u16)bkt;
        }
      }
    }
    __syncthreads();
    for (int i = WIN + t; i < nval; i += PBT) {
      pairS[gbase[stageB[i - WIN]] + i] = stage[i - WIN];
    }
  } else {
    unsigned* stg32 = (unsigned*)stage;
    // ---- D window 0 ----
#pragma unroll
    for (int j = 0; j < EPT_P; j++) {
      if (pk[j] >= 0) {
        int bkt = pk[j] >> 13;
        int idx = ofs[bkt] + (pk[j] & 8191);
        if (idx < WIN) {
          stg32[idx] = ((unsigned)f2bf(ex[j]) << 16) | (unsigned)key[j];
          stageB[idx] = (u16)bkt;
        }
      }
    }
    __syncthreads();
    for (int i = t; i < lim0; i += PBT) {
      pairD[gbase[stageB[i]] + i] = stg32[i];
    }
    __syncthreads();
    // ---- D window 1 ----
#pragma unroll
    for (int j = 0; j < EPT_P; j++) {
      if (pk[j] >= 0) {
        int bkt = pk[j] >> 13;
        int idx = ofs[bkt] + (pk[j] & 8191);
        if (idx >= WIN) {
          stg32[idx - WIN] = ((unsigned)f2bf(ex[j]) << 16) | (unsigned)key[j];
          stageB[idx - WIN] = (u16)bkt;
        }
      }
    }
    __syncthreads();
    for (int i = WIN + t; i < nval; i += PBT) {
      pairD[gbase[stageB[i - WIN]] + i] = stg32[i - WIN];
    }
  }
}

// ---------------------------------------------------------------------------
// denom: grid (NBKTD, 8). Each sub-block takes 1/8 of a coarse dst-bucket's
// fill range, accumulates 1024 LDS partial sums, then flushes nonzero slots
// with low-contention global atomicAdd (~8 adds/counter device-wide).
// denom[] holds the SUM; sortagg applies rcp.
// ---------------------------------------------------------------------------
#define DSUB 8
__global__ __launch_bounds__(256) void k_denom(const int* __restrict__ dfill,
                                               const unsigned* __restrict__ pairD,
                                               float* __restrict__ denom) {
  __shared__ float lacc[1024];
  const int t = threadIdx.x;
  const int c = blockIdx.x;
  const int sub = blockIdx.y;
  for (int i = t; i < 1024; i += 256) lacc[i] = 0.f;
  __syncthreads();
  const int fill = dfill[c << 4];
  const int b0 = c * CAPD + fill * sub / DSUB;
  const int b1 = c * CAPD + fill * (sub + 1) / DSUB;
  for (int i = b0 + t; i < b1; i += 256) {
    unsigned u = pairD[i];
    atomicAdd(&lacc[u & 1023], __uint_as_float(u & 0xFFFF0000u));
  }
  __syncthreads();
  for (int i = t; i < 1024; i += 256) {
    float v = lacc[i];
    if (v != 0.f) {
      int node = c * 1024 + i;
      if (node < N_NODES) atomicAdd(&denom[node], v);
    }
  }
}

// ---------------------------------------------------------------------------
// sortagg: FUSED sort + aggregate. Block (1024 thr) per src-bucket.
// Batched loads (5 pairS reads, then 5 denom gathers), register rank via
// atomicAdd return, scatter att-folded pairs into LDS, aggregate with
// 16 lanes/node float4 acc, hbf row gather, ELU, coalesced out write.
// ---------------------------------------------------------------------------
#define SAT 1024
#define SMAX 5  // ceil(CAP / SAT)
__global__ __launch_bounds__(SAT) void k_sortagg(
    const int* __restrict__ sfill, const float2* __restrict__ pairS,
    const float* __restrict__ denom, const u16* __restrict__ hbf,
    float* __restrict__ out) {
  __shared__ float2 stg[CAP];
  __shared__ int lcnt[128];
  __shared__ int nbeg[128];
  __shared__ int nend[128];
  __shared__ int w0tot;
  const int t = threadIdx.x;
  const int bkt = blockIdx.x;

  if (t < 128) lcnt[t] = 0;
  __syncthreads();

  const int gbeg = bkt * CAP;
  const int ne = sfill[bkt << 4];

  // ---- batched pairS loads ----
  float2 pr[SMAX];
#pragma unroll
  for (int k = 0; k < SMAX; k++) {
    int i = t + k * SAT;
    if (i < ne) pr[k] = pairS[gbeg + i];
  }
  // ---- histogram (rank = return value) ----
  int rk[SMAX];
#pragma unroll
  for (int k = 0; k < SMAX; k++) {
    int i = t + k * SAT;
    if (i < ne) rk[k] = atomicAdd(&lcnt[(__float_as_int(pr[k].y) >> 17) & 127], 1);
  }
  __syncthreads();

  // ---- scan (128 entries over 2 waves) ----
  const int lane = t & 63;
  int v = (t < 128) ? lcnt[t] : 0;
  int val = v;
#pragma unroll
  for (int o = 1; o < 64; o <<= 1) {
    int u = __shfl_up(val, o, 64);
    if (lane >= o) val += u;
  }
  if (t == 63) w0tot = val;
  __syncthreads();
  if (t < 128) {
    int excl = val - v + ((t >= 64) ? w0tot : 0);
    nbeg[t] = excl;
    nend[t] = excl + v;
  }
  __syncthreads();

  // ---- batched denom gathers ----
  float dn[SMAX];
#pragma unroll
  for (int k = 0; k < SMAX; k++) {
    int i = t + k * SAT;
    if (i < ne) dn[k] = denom[__float_as_int(pr[k].y) & 0x1FFFF];
  }
  // ---- scatter into LDS stage with att folded (no atomics) ----
#pragma unroll
  for (int k = 0; k < SMAX; k++) {
    int i = t + k * SAT;
    if (i < ne) {
      int pkv = __float_as_int(pr[k].y);
      int sl = (pkv >> 17) & 127;
      int d = pkv & 0x1FFFF;
      float att = pr[k].x * __builtin_amdgcn_rcpf(dn[k]);
      stg[nbeg[sl] + rk[k]] = make_float2(att, __int_as_float(d));
    }
  }
  __syncthreads();

  // ---- aggregate: 64 groups of 16 lanes; each group 2 nodes ----
  const int G = t >> 4;   // 0..63
  const int sl = t & 15;  // feature quad
  for (int nl = G; nl < 128; nl += 64) {
    int node = bkt * 128 + nl;
    int i = nbeg[nl];
    const int e0 = nend[nl];
    float4 acc = make_float4(0.f, 0.f, 0.f, 0.f);
    for (; i + 1 < e0; i += 2) {
      float2 p0 = stg[i];
      float2 p1 = stg[i + 1];
      int d0 = __float_as_int(p0.y);
      int d1 = __float_as_int(p1.y);
      ushort4 q0 = *(const ushort4*)&hbf[(size_t)d0 * OUT_F + sl * 4];
      ushort4 q1 = *(const ushort4*)&hbf[(size_t)d1 * OUT_F + sl * 4];
      acc.x = fmaf(p0.x, bf2f(q0.x), acc.x);
      acc.y = fmaf(p0.x, bf2f(q0.y), acc.y);
      acc.z = fmaf(p0.x, bf2f(q0.z), acc.z);
      acc.w = fmaf(p0.x, bf2f(q0.w), acc.w);
      acc.x = fmaf(p1.x, bf2f(q1.x), acc.x);
      acc.y = fmaf(p1.x, bf2f(q1.y), acc.y);
      acc.z = fmaf(p1.x, bf2f(q1.z), acc.z);
      acc.w = fmaf(p1.x, bf2f(q1.w), acc.w);
    }
    if (i < e0) {
      float2 p = stg[i];
      int d = __float_as_int(p.y);
      ushort4 q = *(const ushort4*)&hbf[(size_t)d * OUT_F + sl * 4];
      acc.x = fmaf(p.x, bf2f(q.x), acc.x);
      acc.y = fmaf(p.x, bf2f(q.y), acc.y);
      acc.z = fmaf(p.x, bf2f(q.z), acc.z);
      acc.w = fmaf(p.x, bf2f(q.w), acc.w);
    }
    if (node < N_NODES) {
      float4 o;
      o.x = acc.x > 0.f ? acc.x : expm1f(acc.x);
      o.y = acc.y > 0.f ? acc.y : expm1f(acc.y);
      o.z = acc.z > 0.f ? acc.z : expm1f(acc.z);
      o.w = acc.w > 0.f ? acc.w : expm1f(acc.w);
      *(float4*)(out + (size_t)node * OUT_F + sl * 4) = o;
    }
  }
}

// ---------------------------------------------------------------------------
extern "C" void kernel_launch(void* const* d_in, const int* in_sizes, int n_in,
                              void* d_out, int out_size, void* d_ws,
                              size_t ws_size, hipStream_t stream) {
  const int* adj = (const int*)d_in[0];
  const float* x = (const float*)d_in[1];
  const float* W = (const float*)d_in[2];
  const float* b = (const float*)d_in[3];
  const float* a = (const float*)d_in[4];
  float* out = (float*)d_out;

  float* ws = (float*)d_ws;
  float* s1v = ws;                            // 100,000
  float* s2v = ws + 100000;                   // 100,000
  float* denom = ws + 200000;                 // 100,000 (zeroed in prep)
  int* sfill = (int*)(ws + 300000);           // 782*16 ints (padded, 12,512)
  int* dfill = (int*)(ws + 312800);           // 98*16 ints (padded, 1,568)
  float2* pairS = (float2*)(ws + 314400);     // 782*4480 float2 = 7,006,720 f
  unsigned* pairD = (unsigned*)(ws + 7321120);// 98*34304 u32 = 3,361,792 f
  u16* hbf = (u16*)(ws + 10682912);           // 6.4M u16 = 3.2M f
  u16* Wbf = (u16*)(ws + 13882912);           // 16,384 u16 = 8,192 f
  // total ~13.89M floats = 55.6 MB

  const int* src = adj;
  const int* dst = adj + N_EDGES;

  k_prep<<<165, 256, 0, stream>>>(W, Wbf, sfill, dfill, denom);
  k_linear<<<(N_NODES + 63) / 64, 256, 0, stream>>>(x, Wbf, b, a, hbf, s1v, s2v);
  k_place<<<dim3((N_EDGES + PEB - 1) / PEB, 2), PBT, 0, stream>>>(
      src, dst, s1v, s2v, sfill, dfill, pairS, pairD);
  k_denom<<<dim3(NBKTD, DSUB), 256, 0, stream>>>(dfill, pairD, denom);
  k_sortagg<<<NBKT, SAT, 0, stream>>>(sfill, pairS, denom, hbf, out);
}

// Round 10
// 359.558 us; speedup vs baseline: 1.8457x; 1.8457x over previous
//
#include <hip/hip_runtime.h>
#include <math.h>

#define N_NODES 100000
#define N_EDGES 3200000
#define IN_F 256
#define OUT_F 64
#define LRELU_ALPHA 0.2f
#define NBKT 782    // src buckets: 128 nodes each
#define CAP 4480    // src bucket capacity: mean 4096 + 6 sigma
#define NBKTD 98    // dst coarse buckets: 1024 nodes each
#define CAPD 34304  // dst bucket capacity: mean 32653 + ~9 sigma

typedef unsigned short u16;
typedef __attribute__((ext_vector_type(8))) short short8;
typedef __attribute__((ext_vector_type(4))) float floatx4;

__device__ inline u16 f2bf(float f) {  // RNE fp32 -> bf16
  unsigned u = __float_as_uint(f);
  u += 0x7FFFu + ((u >> 16) & 1u);
  return (u16)(u >> 16);
}
__device__ inline float bf2f(u16 h) {
  return __uint_as_float(((unsigned)h) << 16);
}

// ---------------------------------------------------------------------------
// prep: blocks 0..63 convert W to bf16; block 64 zeros fill ctrs (PADDED:
// one counter per 64B line, stride 16 ints); blocks 65..164 zero denom.
// ---------------------------------------------------------------------------
__global__ __launch_bounds__(256) void k_prep(const float* __restrict__ W,
                                              u16* __restrict__ Wbf,
                                              int* __restrict__ sfill,
                                              int* __restrict__ dfill,
                                              float* __restrict__ denom) {
  if (blockIdx.x < 64) {
    int i = blockIdx.x * 256 + threadIdx.x;
    Wbf[i] = f2bf(W[i]);
  } else if (blockIdx.x == 64) {
    for (int i = threadIdx.x; i < NBKT * 16; i += 256) sfill[i] = 0;
    for (int i = threadIdx.x; i < NBKTD * 16; i += 256) dfill[i] = 0;
  } else {
    int i4 = (blockIdx.x - 65) * 256 + threadIdx.x;
    if (i4 < 25000) {
      ((float4*)denom)[i4] = make_float4(0.f, 0.f, 0.f, 0.f);
    }
  }
}

// ---------------------------------------------------------------------------
// linear via bf16 MFMA: h = x@W^T + b (stored bf16); s1 = h.a1; s2 = h.a2
// ---------------------------------------------------------------------------
__global__ __launch_bounds__(256) void k_linear(
    const float* __restrict__ x, const u16* __restrict__ Wbf,
    const float* __restrict__ b, const float* __restrict__ a,
    u16* __restrict__ hbf, float* __restrict__ s1, float* __restrict__ s2) {
  __shared__ u16 Wlds[64 * 264];

  const int t = threadIdx.x;
#pragma unroll
  for (int p = 0; p < 8; p++) {
    int c = p * 256 + t;
    int row = c >> 5;
    int kc = (c & 31) * 8;
    *(short8*)&Wlds[row * 264 + kc] = *(const short8*)&Wbf[row * 256 + kc];
  }
  __syncthreads();

  const int w = t >> 6;
  const int lane = t & 63;
  const int col = lane & 15;
  const int q = lane >> 4;
  const int m0 = blockIdx.x * 64 + w * 16;

  floatx4 acc[4];
#pragma unroll
  for (int nt = 0; nt < 4; nt++) acc[nt] = (floatx4){0.f, 0.f, 0.f, 0.f};

  int mrow = m0 + col;
  if (mrow > N_NODES - 1) mrow = N_NODES - 1;
  const float* xrow = x + (size_t)mrow * IN_F + q * 8;

#pragma unroll
  for (int kk = 0; kk < 8; kk++) {
    float4 f0 = *(const float4*)(xrow + kk * 32);
    float4 f1 = *(const float4*)(xrow + kk * 32 + 4);
    short8 af;
    af[0] = (short)f2bf(f0.x);
    af[1] = (short)f2bf(f0.y);
    af[2] = (short)f2bf(f0.z);
    af[3] = (short)f2bf(f0.w);
    af[4] = (short)f2bf(f1.x);
    af[5] = (short)f2bf(f1.y);
    af[6] = (short)f2bf(f1.z);
    af[7] = (short)f2bf(f1.w);
#pragma unroll
    for (int nt = 0; nt < 4; nt++) {
      short8 bfr = *(const short8*)&Wlds[(nt * 16 + col) * 264 + kk * 32 + q * 8];
      acc[nt] = __builtin_amdgcn_mfma_f32_16x16x32_bf16(af, bfr, acc[nt], 0, 0, 0);
    }
  }

  float bv[4], a1v[4], a2v[4];
#pragma unroll
  for (int nt = 0; nt < 4; nt++) {
    bv[nt] = b[nt * 16 + col];
    a1v[nt] = a[nt * 16 + col];
    a2v[nt] = a[OUT_F + nt * 16 + col];
  }
#pragma unroll
  for (int r = 0; r < 4; r++) {
    int node = m0 + q * 4 + r;
    float p1 = 0.f, p2 = 0.f;
#pragma unroll
    for (int nt = 0; nt < 4; nt++) {
      float hv = acc[nt][r] + bv[nt];
      if (node < N_NODES) hbf[(size_t)node * OUT_F + nt * 16 + col] = f2bf(hv);
      p1 = fmaf(hv, a1v[nt], p1);
      p2 = fmaf(hv, a2v[nt], p2);
    }
#pragma unroll
    for (int s = 1; s < 16; s <<= 1) {
      p1 += __shfl_xor(p1, s, 16);
      p2 += __shfl_xor(p2, s, 16);
    }
    if (col == 0 && node < N_NODES) {
      s1[node] = p1;
      s2[node] = p2;
    }
  }
}

// ---------------------------------------------------------------------------
// place: ex = exp(leakyrelu(s1[src]+s2[dst])); write into PADDED buckets.
// R10: EXACT R7 structure (EPT_P=8 -- the measured sweet spot: R8's span-2048
// doubled write amp, R9's span-8192 spilled to scratch at 1 GB traffic).
// Keeps R8's line-padded fill counters + gbase-ofs fold.
// pairS = float2 (ex, d | (s&127)<<17)  src-bucketed (128-node)
// pairD = u32 (bf16(ex)<<16 | d&1023)   dst-bucketed (1024-node)
// ---------------------------------------------------------------------------
#define PBT 512
#define EPT_P 8
#define PEB (PBT * EPT_P)  // 4096 edges per block
__global__ __launch_bounds__(PBT, 6) void k_place(
    const int* __restrict__ src, const int* __restrict__ dst,
    const float* __restrict__ s1, const float* __restrict__ s2,
    int* __restrict__ sfill, int* __restrict__ dfill,
    float2* __restrict__ pairS, unsigned* __restrict__ pairD) {
  __shared__ int lc[NBKT];     // histogram (counts after pass 1)
  __shared__ int ofs[NBKT];    // block-local stage offset
  __shared__ int gbase[NBKT];  // (bkt*cap + fillbase - ofs)
  __shared__ int tot;          // block-local stage allocator
  __shared__ float2 stage[PEB];
  __shared__ u16 stageB[PEB];  // bucket id per stage entry

  const int t = threadIdx.x;
  const int side = blockIdx.y;  // 0 = S (src-bucket), 1 = D (dst-bucket)
  const int base = blockIdx.x * PEB + t;
  const int nb = side ? NBKTD : NBKT;

  for (int i = t; i < nb; i += PBT) lc[i] = 0;
  if (t == 0) tot = 0;
  __syncthreads();

  // ---- pass A: all adj loads in flight ----
  int sa[EPT_P], da[EPT_P];
#pragma unroll
  for (int j = 0; j < EPT_P; j++) {
    int e = base + j * PBT;
    int ec = e < N_EDGES ? e : N_EDGES - 1;
    sa[j] = src[ec];
    da[j] = dst[ec];
  }
  // ---- pass B: all s1/s2 gathers in flight ----
  float g1[EPT_P], g2[EPT_P];
#pragma unroll
  for (int j = 0; j < EPT_P; j++) {
    g1[j] = s1[sa[j]];
    g2[j] = s2[da[j]];
  }
  // ---- pass C: math + keys ----
  float ex[EPT_P];
  int key[EPT_P], bk[EPT_P], rk[EPT_P];
#pragma unroll
  for (int j = 0; j < EPT_P; j++) {
    float v = g1[j] + g2[j];
    v = v > 0.f ? v : LRELU_ALPHA * v;
    ex[j] = __expf(v);
    if (side == 0) {
      key[j] = da[j] | ((sa[j] & 127) << 17);
      bk[j] = sa[j] >> 7;
    } else {
      key[j] = da[j] & 1023;
      bk[j] = da[j] >> 10;
    }
    if (base + j * PBT >= N_EDGES) bk[j] = -1;
  }
  // ---- pass D: count (rank = return value) ----
#pragma unroll
  for (int j = 0; j < EPT_P; j++) {
    if (bk[j] >= 0) rk[j] = atomicAdd(&lc[bk[j]], 1);
  }
  __syncthreads();

  // ---- reserve global + local ranges (padded counters: stride 16) ----
  int* fill = side ? dfill : sfill;
  const int capb = side ? CAPD : CAP;
  for (int i = t; i < nb; i += PBT) {
    int c = lc[i];
    if (c) {
      int o = atomicAdd(&tot, c);
      ofs[i] = o;
      gbase[i] = i * capb + atomicAdd(&fill[i << 4], c) - o;
    }
  }
  __syncthreads();
  const int nval = tot;  // # valid edges this block

  if (side == 0) {
    // ---- S: scatter to stage at saved rank ----
#pragma unroll
    for (int j = 0; j < EPT_P; j++) {
      if (bk[j] >= 0) {
        int idx = ofs[bk[j]] + rk[j];
        stage[idx] = make_float2(ex[j], __int_as_float(key[j]));
        stageB[idx] = (u16)bk[j];
      }
    }
    __syncthreads();
    // ---- S: coalesced flush ----
    for (int i = t; i < nval; i += PBT) {
      pairS[gbase[stageB[i]] + i] = stage[i];
    }
  } else {
    // ---- D: scatter to stage (packed u32) at saved rank ----
    unsigned* stg32 = (unsigned*)stage;
#pragma unroll
    for (int j = 0; j < EPT_P; j++) {
      if (bk[j] >= 0) {
        int idx = ofs[bk[j]] + rk[j];
        stg32[idx] = ((unsigned)f2bf(ex[j]) << 16) | (unsigned)key[j];
        stageB[idx] = (u16)bk[j];
      }
    }
    __syncthreads();
    // ---- D: coalesced flush ----
    for (int i = t; i < nval; i += PBT) {
      pairD[gbase[stageB[i]] + i] = stg32[i];
    }
  }
}

// ---------------------------------------------------------------------------
// denom: grid (NBKTD, 8). Each sub-block takes 1/8 of a coarse dst-bucket's
// fill range, accumulates 1024 LDS partial sums, then flushes nonzero slots
// with low-contention global atomicAdd (~8 adds/counter device-wide).
// denom[] holds the SUM; sortagg applies rcp.
// ---------------------------------------------------------------------------
#define DSUB 8
__global__ __launch_bounds__(256) void k_denom(const int* __restrict__ dfill,
                                               const unsigned* __restrict__ pairD,
                                               float* __restrict__ denom) {
  __shared__ float lacc[1024];
  const int t = threadIdx.x;
  const int c = blockIdx.x;
  const int sub = blockIdx.y;
  for (int i = t; i < 1024; i += 256) lacc[i] = 0.f;
  __syncthreads();
  const int fill = dfill[c << 4];
  const int b0 = c * CAPD + fill * sub / DSUB;
  const int b1 = c * CAPD + fill * (sub + 1) / DSUB;
  for (int i = b0 + t; i < b1; i += 256) {
    unsigned u = pairD[i];
    atomicAdd(&lacc[u & 1023], __uint_as_float(u & 0xFFFF0000u));
  }
  __syncthreads();
  for (int i = t; i < 1024; i += 256) {
    float v = lacc[i];
    if (v != 0.f) {
      int node = c * 1024 + i;
      if (node < N_NODES) atomicAdd(&denom[node], v);
    }
  }
}

// ---------------------------------------------------------------------------
// sortagg: FUSED sort + aggregate. Block per src-bucket.
// R10: SAT 1024->512 (SMAX 9). LDS ~37 KB -> 4 resident blocks/CU (was
// thread-capped at 2) -> 782 blocks fit in ONE scheduling wave (0.76) vs
// 1.53 -> kills the ~35% tail and doubles latency-hiding block count.
// ---------------------------------------------------------------------------
#define SAT 512
#define SMAX 9  // ceil(CAP / SAT)
__global__ __launch_bounds__(SAT) void k_sortagg(
    const int* __restrict__ sfill, const float2* __restrict__ pairS,
    const float* __restrict__ denom, const u16* __restrict__ hbf,
    float* __restrict__ out) {
  __shared__ float2 stg[CAP];
  __shared__ int lcnt[128];
  __shared__ int nbeg[128];
  __shared__ int nend[128];
  __shared__ int w0tot;
  const int t = threadIdx.x;
  const int bkt = blockIdx.x;

  if (t < 128) lcnt[t] = 0;
  __syncthreads();

  const int gbeg = bkt * CAP;
  const int ne = sfill[bkt << 4];

  // ---- batched pairS loads ----
  float2 pr[SMAX];
#pragma unroll
  for (int k = 0; k < SMAX; k++) {
    int i = t + k * SAT;
    if (i < ne) pr[k] = pairS[gbeg + i];
  }
  // ---- histogram (rank = return value) ----
  int rk[SMAX];
#pragma unroll
  for (int k = 0; k < SMAX; k++) {
    int i = t + k * SAT;
    if (i < ne) rk[k] = atomicAdd(&lcnt[(__float_as_int(pr[k].y) >> 17) & 127], 1);
  }
  __syncthreads();

  // ---- scan (128 entries over 2 waves) ----
  const int lane = t & 63;
  int v = (t < 128) ? lcnt[t] : 0;
  int val = v;
#pragma unroll
  for (int o = 1; o < 64; o <<= 1) {
    int u = __shfl_up(val, o, 64);
    if (lane >= o) val += u;
  }
  if (t == 63) w0tot = val;
  __syncthreads();
  if (t < 128) {
    int excl = val - v + ((t >= 64) ? w0tot : 0);
    nbeg[t] = excl;
    nend[t] = excl + v;
  }
  __syncthreads();

  // ---- batched denom gathers ----
  float dn[SMAX];
#pragma unroll
  for (int k = 0; k < SMAX; k++) {
    int i = t + k * SAT;
    if (i < ne) dn[k] = denom[__float_as_int(pr[k].y) & 0x1FFFF];
  }
  // ---- scatter into LDS stage with att folded (no atomics) ----
#pragma unroll
  for (int k = 0; k < SMAX; k++) {
    int i = t + k * SAT;
    if (i < ne) {
      int pkv = __float_as_int(pr[k].y);
      int sl = (pkv >> 17) & 127;
      int d = pkv & 0x1FFFF;
      float att = pr[k].x * __builtin_amdgcn_rcpf(dn[k]);
      stg[nbeg[sl] + rk[k]] = make_float2(att, __int_as_float(d));
    }
  }
  __syncthreads();

  // ---- aggregate: 32 groups of 16 lanes; each group 4 nodes ----
  const int G = t >> 4;   // 0..31
  const int sl = t & 15;  // feature quad
  for (int nl = G; nl < 128; nl += 32) {
    int node = bkt * 128 + nl;
    int i = nbeg[nl];
    const int e0 = nend[nl];
    float4 acc = make_float4(0.f, 0.f, 0.f, 0.f);
    for (; i + 1 < e0; i += 2) {
      float2 p0 = stg[i];
      float2 p1 = stg[i + 1];
      int d0 = __float_as_int(p0.y);
      int d1 = __float_as_int(p1.y);
      ushort4 q0 = *(const ushort4*)&hbf[(size_t)d0 * OUT_F + sl * 4];
      ushort4 q1 = *(const ushort4*)&hbf[(size_t)d1 * OUT_F + sl * 4];
      acc.x = fmaf(p0.x, bf2f(q0.x), acc.x);
      acc.y = fmaf(p0.x, bf2f(q0.y), acc.y);
      acc.z = fmaf(p0.x, bf2f(q0.z), acc.z);
      acc.w = fmaf(p0.x, bf2f(q0.w), acc.w);
      acc.x = fmaf(p1.x, bf2f(q1.x), acc.x);
      acc.y = fmaf(p1.x, bf2f(q1.y), acc.y);
      acc.z = fmaf(p1.x, bf2f(q1.z), acc.z);
      acc.w = fmaf(p1.x, bf2f(q1.w), acc.w);
    }
    if (i < e0) {
      float2 p = stg[i];
      int d = __float_as_int(p.y);
      ushort4 q = *(const ushort4*)&hbf[(size_t)d * OUT_F + sl * 4];
      acc.x = fmaf(p.x, bf2f(q.x), acc.x);
      acc.y = fmaf(p.x, bf2f(q.y), acc.y);
      acc.z = fmaf(p.x, bf2f(q.z), acc.z);
      acc.w = fmaf(p.x, bf2f(q.w), acc.w);
    }
    if (node < N_NODES) {
      float4 o;
      o.x = acc.x > 0.f ? acc.x : expm1f(acc.x);
      o.y = acc.y > 0.f ? acc.y : expm1f(acc.y);
      o.z = acc.z > 0.f ? acc.z : expm1f(acc.z);
      o.w = acc.w > 0.f ? acc.w : expm1f(acc.w);
      *(float4*)(out + (size_t)node * OUT_F + sl * 4) = o;
    }
  }
}

// ---------------------------------------------------------------------------
extern "C" void kernel_launch(void* const* d_in, const int* in_sizes, int n_in,
                              void* d_out, int out_size, void* d_ws,
                              size_t ws_size, hipStream_t stream) {
  const int* adj = (const int*)d_in[0];
  const float* x = (const float*)d_in[1];
  const float* W = (const float*)d_in[2];
  const float* b = (const float*)d_in[3];
  const float* a = (const float*)d_in[4];
  float* out = (float*)d_out;

  float* ws = (float*)d_ws;
  float* s1v = ws;                            // 100,000
  float* s2v = ws + 100000;                   // 100,000
  float* denom = ws + 200000;                 // 100,000 (zeroed in prep)
  int* sfill = (int*)(ws + 300000);           // 782*16 ints (padded, 12,512)
  int* dfill = (int*)(ws + 312800);           // 98*16 ints (padded, 1,568)
  float2* pairS = (float2*)(ws + 314400);     // 782*4480 float2 = 7,006,720 f
  unsigned* pairD = (unsigned*)(ws + 7321120);// 98*34304 u32 = 3,361,792 f
  u16* hbf = (u16*)(ws + 10682912);           // 6.4M u16 = 3.2M f
  u16* Wbf = (u16*)(ws + 13882912);           // 16,384 u16 = 8,192 f
  // total ~13.89M floats = 55.6 MB

  const int* src = adj;
  const int* dst = adj + N_EDGES;

  k_prep<<<165, 256, 0, stream>>>(W, Wbf, sfill, dfill, denom);
  k_linear<<<(N_NODES + 63) / 64, 256, 0, stream>>>(x, Wbf, b, a, hbf, s1v, s2v);
  k_place<<<dim3((N_EDGES + PEB - 1) / PEB, 2), PBT, 0, stream>>>(
      src, dst, s1v, s2v, sfill, dfill, pairS, pairD);
  k_denom<<<dim3(NBKTD, DSUB), 256, 0, stream>>>(dfill, pairD, denom);
  k_sortagg<<<NBKT, SAT, 0, stream>>>(sfill, pairS, denom, hbf, out);
}